// Round 2
// baseline (1566.063 us; speedup 1.0000x reference)
//
#include <hip/hip_runtime.h>

#define BB 32
#define CC 512
#define HWN 1024
#define DD 64
#define OO 640  // 2*DD + CC

// ---------------- BN stats: one block (256 thr) per channel ----------------
__global__ __launch_bounds__(256) void bn_stats_kernel(const float* __restrict__ x,
                                                       float* __restrict__ mean,
                                                       float* __restrict__ rstd) {
    int c = blockIdx.x;
    int t = threadIdx.x;
    float s = 0.f, s2 = 0.f;
    for (int b = 0; b < BB; ++b) {
        const float* p = x + ((size_t)b * CC + c) * HWN;
        for (int i = t; i < HWN; i += 256) {
            float v = p[i];
            s += v; s2 += v * v;
        }
    }
    for (int off = 32; off > 0; off >>= 1) {
        s  += __shfl_down(s,  off, 64);
        s2 += __shfl_down(s2, off, 64);
    }
    __shared__ float sh[4], sh2[4];
    int wave = t >> 6;
    if ((t & 63) == 0) { sh[wave] = s; sh2[wave] = s2; }
    __syncthreads();
    if (t == 0) {
        float ts = 0.f, ts2 = 0.f;
        for (int w = 0; w < 4; ++w) { ts += sh[w]; ts2 += sh2[w]; }
        const float invN = 1.f / (float)(BB * HWN);
        float m = ts * invN;
        float var = ts2 * invN - m * m;
        mean[c] = m;
        rstd[c] = rsqrtf(var + 1e-5f);
    }
}

// ---------------- BN apply (+optional ReLU), float4 elementwise ----------------
template <bool RELU>
__global__ __launch_bounds__(256) void bn_apply_kernel(const float* __restrict__ x,
                                                       const float* __restrict__ mean,
                                                       const float* __restrict__ rstd,
                                                       const float* __restrict__ g,
                                                       const float* __restrict__ bta,
                                                       float* __restrict__ out) {
    size_t idx = (size_t)blockIdx.x * 256 + threadIdx.x;   // float4 index
    int c = (int)((idx >> 8) & (CC - 1));                  // (idx*4 / 1024) % 512
    float4 v = ((const float4*)x)[idx];
    float r = rstd[c] * g[c];
    float sh = bta[c] - mean[c] * r;
    float4 o;
    o.x = fmaf(v.x, r, sh);
    o.y = fmaf(v.y, r, sh);
    o.z = fmaf(v.z, r, sh);
    o.w = fmaf(v.w, r, sh);
    if (RELU) {
        o.x = fmaxf(o.x, 0.f); o.y = fmaxf(o.y, 0.f);
        o.z = fmaxf(o.z, 0.f); o.w = fmaxf(o.w, 0.f);
    }
    ((float4*)out)[idx] = o;
}

// ---------------- softmax over q (axis=1), 2-pass down columns ----------------
__global__ __launch_bounds__(256) void softmax_q_kernel(float* __restrict__ beta) {
    int b = blockIdx.y;
    int k = blockIdx.x * 256 + threadIdx.x;
    float* p = beta + (size_t)b * HWN * HWN + k;
    float m = -1e30f, s = 0.f;
    for (int q = 0; q < HWN; ++q) {
        float v = p[(size_t)q * HWN];
        float nm = fmaxf(m, v);
        s = s * __expf(m - nm) + __expf(v - nm);
        m = nm;
    }
    float inv = 1.f / s;
    for (int q = 0; q < HWN; ++q) {
        float v = p[(size_t)q * HWN];
        p[(size_t)q * HWN] = __expf(v - m) * inv;
    }
}

// ---------------- tiled fp32 GEMM: C[b] = scale*(A @ B[b]) (+bias)(+relu)(+resid) ----
// A: MxK row-major (lda=K-stride) or, if TRANSA, KxM (lda = M-row stride).
// B: KxN with row stride HWN. C: row stride HWN.
// BM=BN=64, BK=16, 256 threads, 4x4 per thread.
template <bool TRANSA, bool BIAS, bool RELU, bool RESID>
__global__ __launch_bounds__(256) void gemm_kernel(const float* __restrict__ A,
                                                   const float* __restrict__ B,
                                                   const float* __restrict__ bias,
                                                   const float* __restrict__ resid,
                                                   float* __restrict__ C,
                                                   int K, int lda,
                                                   long strideA, long strideB, long strideC,
                                                   float scale) {
    __shared__ float As[16][64];
    __shared__ float Bs[16][64];
    int b  = blockIdx.z;
    int n0 = blockIdx.x * 64;
    int m0 = blockIdx.y * 64;
    const float* Ab = A + (size_t)b * strideA;
    const float* Bb = B + (size_t)b * strideB;
    int tid = threadIdx.x;
    int tx = tid & 15, ty = tid >> 4;
    float acc[4][4] = {};

    for (int k0 = 0; k0 < K; k0 += 16) {
        if (TRANSA) {
            int kk = tid >> 4;
            int m4 = (tid & 15) * 4;
            float4 av = *(const float4*)(Ab + (size_t)(k0 + kk) * lda + m0 + m4);
            *(float4*)&As[kk][m4] = av;
        } else {
            int row = tid >> 2;
            int c4  = (tid & 3) * 4;
            float4 av = *(const float4*)(Ab + (size_t)(m0 + row) * lda + k0 + c4);
            As[c4 + 0][row] = av.x;
            As[c4 + 1][row] = av.y;
            As[c4 + 2][row] = av.z;
            As[c4 + 3][row] = av.w;
        }
        {
            int kk = tid >> 4;
            int n4 = (tid & 15) * 4;
            float4 bv = *(const float4*)(Bb + (size_t)(k0 + kk) * HWN + n0 + n4);
            *(float4*)&Bs[kk][n4] = bv;
        }
        __syncthreads();
#pragma unroll
        for (int kk = 0; kk < 16; ++kk) {
            float4 a  = *(const float4*)&As[kk][ty * 4];
            float4 bv = *(const float4*)&Bs[kk][tx * 4];
            float av[4] = {a.x, a.y, a.z, a.w};
            float bw[4] = {bv.x, bv.y, bv.z, bv.w};
#pragma unroll
            for (int i = 0; i < 4; ++i)
#pragma unroll
                for (int j = 0; j < 4; ++j)
                    acc[i][j] = fmaf(av[i], bw[j], acc[i][j]);
        }
        __syncthreads();
    }

    float* Cb = C + (size_t)b * strideC;
    const float* Rb = RESID ? (resid + (size_t)b * strideC) : nullptr;
#pragma unroll
    for (int i = 0; i < 4; ++i) {
        int m = m0 + ty * 4 + i;
        float bi = BIAS ? bias[m] : 0.f;
        size_t rowoff = (size_t)m * HWN + n0 + tx * 4;
        float4 o;
        float v0 = acc[i][0] * scale + bi;
        float v1 = acc[i][1] * scale + bi;
        float v2 = acc[i][2] * scale + bi;
        float v3 = acc[i][3] * scale + bi;
        if (RELU) {
            v0 = fmaxf(v0, 0.f); v1 = fmaxf(v1, 0.f);
            v2 = fmaxf(v2, 0.f); v3 = fmaxf(v3, 0.f);
        }
        if (RESID) {
            float4 rv = *(const float4*)(Rb + rowoff);
            v0 += rv.x; v1 += rv.y; v2 += rv.z; v3 += rv.w;
        }
        o.x = v0; o.y = v1; o.z = v2; o.w = v3;
        *(float4*)(Cb + rowoff) = o;
    }
}

extern "C" void kernel_launch(void* const* d_in, const int* in_sizes, int n_in,
                              void* d_out, int out_size, void* d_ws, size_t ws_size,
                              hipStream_t stream) {
    const float* x     = (const float*)d_in[0];
    const float* bn1_g = (const float*)d_in[1];
    const float* bn1_b = (const float*)d_in[2];
    const float* W_qkv = (const float*)d_in[3];
    const float* b_qkv = (const float*)d_in[4];
    const float* bn2_g = (const float*)d_in[5];
    const float* bn2_b = (const float*)d_in[6];
    const float* W1    = (const float*)d_in[7];
    const float* b1    = (const float*)d_in[8];
    const float* W2    = (const float*)d_in[9];
    const float* b2    = (const float*)d_in[10];
    float* out = (float*)d_out;
    float* ws  = (float*)d_ws;

    // Aliased workspace plan (~208 MB total):
    //  slot A (20,971,520 floats): qkv (steps 3-6) -> ybn (steps 8-9)
    //  slot B (33,554,432 floats): h (2-3) -> beta (4-6) -> y1 (9-10)
    //  xr lives in d_out (6-10); final GEMM rewrites d_out in place
    //  (each thread reads its own residual element before storing: safe).
    float* slotA = ws;                      // 20,971,520 floats
    float* slotB = ws + 20971520;           // 33,554,432 floats
    float* stats = ws + 54525952;           // 2048 floats
    float* mean1 = stats,        *rstd1 = stats + 512;
    float* mean2 = stats + 1024, *rstd2 = stats + 1536;

    float* h    = slotB;
    float* qkv  = slotA;
    float* beta = slotB;
    float* xr   = out;
    float* ybn  = slotA;
    float* y1   = slotB;

    const long sBCH = (long)CC * HWN;   // 512*1024
    const long sBOH = (long)OO * HWN;   // 640*1024
    const long sBQQ = (long)HWN * HWN;  // 1024*1024

    // 1. bn1 stats
    bn_stats_kernel<<<CC, 256, 0, stream>>>(x, mean1, rstd1);
    // 2. h = relu(bn1(x))
    bn_apply_kernel<true><<<(BB * CC * HWN) / 1024, 256, 0, stream>>>(x, mean1, rstd1, bn1_g, bn1_b, h);
    // 3. qkv = W_qkv @ h + b_qkv        (M=640,K=512,N=1024)
    gemm_kernel<false, true, false, false><<<dim3(16, 10, 32), 256, 0, stream>>>(
        W_qkv, h, b_qkv, nullptr, qkv, 512, 512, 0, sBCH, sBOH, 1.f);
    // 4. beta = (q^T k) / 8             (TRANSA, M=1024,K=64,N=1024) — overwrites h (dead)
    gemm_kernel<true, false, false, false><<<dim3(16, 16, 32), 256, 0, stream>>>(
        qkv, qkv + (size_t)DD * HWN, nullptr, nullptr, beta,
        DD, HWN, sBOH, sBOH, sBQQ, 0.125f);
    // 5. softmax over q
    softmax_q_kernel<<<dim3(HWN / 256, BB), 256, 0, stream>>>(beta);
    // 6. xr = v @ beta + x              (M=512,K=1024,N=1024) -> d_out
    gemm_kernel<false, false, false, true><<<dim3(16, 8, 32), 256, 0, stream>>>(
        qkv + (size_t)2 * DD * HWN, beta, nullptr, x, xr,
        HWN, HWN, sBOH, sBQQ, sBCH, 1.f);
    // 7. bn2 stats on xr
    bn_stats_kernel<<<CC, 256, 0, stream>>>(xr, mean2, rstd2);
    // 8. ybn = bn2(xr)                  — overwrites qkv (dead)
    bn_apply_kernel<false><<<(BB * CC * HWN) / 1024, 256, 0, stream>>>(xr, mean2, rstd2, bn2_g, bn2_b, ybn);
    // 9. y1 = relu(W1 @ ybn + b1)       (M=512,K=512,N=1024) — overwrites beta (dead)
    gemm_kernel<false, true, true, false><<<dim3(16, 8, 32), 256, 0, stream>>>(
        W1, ybn, b1, nullptr, y1, 512, 512, 0, sBCH, sBCH, 1.f);
    // 10. out = W2 @ y1 + b2 + xr       (in-place on d_out: per-thread read-then-write)
    gemm_kernel<false, true, false, true><<<dim3(16, 8, 32), 256, 0, stream>>>(
        W2, y1, b2, xr, out, 512, 512, 0, sBCH, sBCH, 1.f);
}

// Round 3
// 515.582 us; speedup vs baseline: 3.0375x; 3.0375x over previous
//
#include <hip/hip_runtime.h>

#define BB 32
#define CC 512
#define HWN 1024
#define DD 64
#define OO 640  // 2*DD + CC

typedef short bf16x8 __attribute__((ext_vector_type(8)));
typedef float f32x4 __attribute__((ext_vector_type(4)));

__device__ __forceinline__ unsigned short f2bf(float f) {
    unsigned int u = __float_as_uint(f);
    unsigned int r = u + 0x7FFFu + ((u >> 16) & 1u);  // RNE
    return (unsigned short)(r >> 16);
}
__device__ __forceinline__ float bf2f(unsigned short h) {
    return __uint_as_float(((unsigned int)h) << 16);
}

// ---------------- f32 -> bf16 convert (weights) ----------------
__global__ __launch_bounds__(256) void cvt_bf16_kernel(const float* __restrict__ in,
                                                       unsigned short* __restrict__ out, int n) {
    int i = blockIdx.x * 256 + threadIdx.x;
    if (i < n) out[i] = f2bf(in[i]);
}

// ---------------- BN stats: one block per channel ----------------
__global__ __launch_bounds__(256) void bn_stats_kernel(const float* __restrict__ x,
                                                       float* __restrict__ mean,
                                                       float* __restrict__ rstd) {
    int c = blockIdx.x;
    int t = threadIdx.x;
    float s = 0.f, s2 = 0.f;
    for (int b = 0; b < BB; ++b) {
        const float* p = x + ((size_t)b * CC + c) * HWN;
        for (int i = t; i < HWN; i += 256) {
            float v = p[i];
            s += v; s2 += v * v;
        }
    }
    for (int off = 32; off > 0; off >>= 1) {
        s  += __shfl_down(s,  off, 64);
        s2 += __shfl_down(s2, off, 64);
    }
    __shared__ float sh[4], sh2[4];
    int wave = t >> 6;
    if ((t & 63) == 0) { sh[wave] = s; sh2[wave] = s2; }
    __syncthreads();
    if (t == 0) {
        float ts = 0.f, ts2 = 0.f;
        for (int w = 0; w < 4; ++w) { ts += sh[w]; ts2 += sh2[w]; }
        const float invN = 1.f / (float)(BB * HWN);
        float m = ts * invN;
        float var = ts2 * invN - m * m;
        mean[c] = m;
        rstd[c] = rsqrtf(var + 1e-5f);
    }
}

// ------- BN apply + transpose: x[b][c][s] f32 -> outT[b][s][c] bf16 (+relu) -------
template <bool RELU>
__global__ __launch_bounds__(256) void bn_apply_t_kernel(const float* __restrict__ x,
                                                         const float* __restrict__ mean,
                                                         const float* __restrict__ rstd,
                                                         const float* __restrict__ g,
                                                         const float* __restrict__ bta,
                                                         unsigned short* __restrict__ outT) {
    __shared__ float tile[64][65];
    int b  = blockIdx.z;
    int c0 = blockIdx.y * 64;
    int s0 = blockIdx.x * 64;
    int t = threadIdx.x;
    int sl = t & 63, grp = t >> 6;  // grp is wave-uniform
    const float* xb = x + ((size_t)b * CC + c0) * HWN + s0;
#pragma unroll
    for (int i = 0; i < 16; ++i) {
        int cr = i * 4 + grp;
        int c = c0 + cr;
        float r  = rstd[c] * g[c];
        float sh = bta[c] - mean[c] * r;
        float v = fmaf(xb[(size_t)cr * HWN + sl], r, sh);
        if (RELU) v = fmaxf(v, 0.f);
        tile[cr][sl] = v;
    }
    __syncthreads();
    unsigned short* ob = outT + ((size_t)b * HWN + s0) * CC + c0;
#pragma unroll
    for (int i = 0; i < 16; ++i) {
        int srow = i * 4 + grp;
        ob[(size_t)srow * CC + sl] = f2bf(tile[sl][srow]);
    }
}

// ---------------- row softmax on bf16 [nrows][1024], in place ----------------
__global__ __launch_bounds__(256) void softmax_row_kernel(unsigned short* __restrict__ p) {
    int row = blockIdx.x * 4 + (threadIdx.x >> 6);
    int L = threadIdx.x & 63;
    unsigned short* pr = p + (size_t)row * HWN;
    uint4 d0 = *(const uint4*)(pr + L * 16);
    uint4 d1 = *(const uint4*)(pr + L * 16 + 8);
    float v[16];
    unsigned int w[8] = {d0.x, d0.y, d0.z, d0.w, d1.x, d1.y, d1.z, d1.w};
#pragma unroll
    for (int i = 0; i < 8; ++i) {
        v[2 * i]     = bf2f((unsigned short)(w[i] & 0xffffu));
        v[2 * i + 1] = bf2f((unsigned short)(w[i] >> 16));
    }
    float m = -1e30f;
#pragma unroll
    for (int i = 0; i < 16; ++i) m = fmaxf(m, v[i]);
    for (int off = 32; off > 0; off >>= 1) m = fmaxf(m, __shfl_xor(m, off, 64));
    float s = 0.f;
#pragma unroll
    for (int i = 0; i < 16; ++i) { v[i] = __expf(v[i] - m); s += v[i]; }
    for (int off = 32; off > 0; off >>= 1) s += __shfl_xor(s, off, 64);
    float inv = 1.f / s;
    unsigned int o[8];
#pragma unroll
    for (int i = 0; i < 8; ++i) {
        unsigned int lo = f2bf(v[2 * i] * inv);
        unsigned int hi = f2bf(v[2 * i + 1] * inv);
        o[i] = lo | (hi << 16);
    }
    *(uint4*)(pr + L * 16)     = make_uint4(o[0], o[1], o[2], o[3]);
    *(uint4*)(pr + L * 16 + 8) = make_uint4(o[4], o[5], o[6], o[7]);
}

// ---------------- MFMA bf16 GEMM: C[b] = scale*(A @ Bt^T) (+bias)(+relu)(+resid) ----
// A:  M x K bf16, row-major, leading dim lda (k-contiguous)
// Bt: N x K bf16, row-major, leading dim ldb (k-contiguous)
// C:  M x N, leading dim ldc; fp32 or bf16. resid: fp32, same geometry as C.
// Tile 128x128, BK=32, 256 threads = 4 waves (2x2 of 64x64), 16 MFMA tiles/wave.
template <bool OUTBF16, int BIASMODE /*0 none,1 row,2 col*/, bool RELU, bool RESID>
__global__ __launch_bounds__(256) void mfma_gemm(const unsigned short* __restrict__ A,
                                                 const unsigned short* __restrict__ Bt,
                                                 const float* __restrict__ bias,
                                                 const float* __restrict__ resid,
                                                 void* __restrict__ C,
                                                 int K, int lda, int ldb, int ldc,
                                                 long strideA, long strideB, long strideC,
                                                 float scale) {
    __shared__ __align__(16) unsigned short As[128 * 32];
    __shared__ __align__(16) unsigned short Bs[128 * 32];
    int b  = blockIdx.z;
    int m0 = blockIdx.y * 128;
    int n0 = blockIdx.x * 128;
    const unsigned short* Ab = A  + (size_t)b * strideA;
    const unsigned short* Bb = Bt + (size_t)b * strideB;
    int t = threadIdx.x;
    int wv = t >> 6, L = t & 63;
    int wm = (wv >> 1) * 64, wn = (wv & 1) * 64;
    int lr = L & 15, lq = L >> 4;
    int srow = t >> 2;          // 0..63
    int skof = (t & 3) * 8;     // 0,8,16,24 (bf16 elems)

    f32x4 acc[4][4] = {};

    for (int k0 = 0; k0 < K; k0 += 32) {
        uint4 a0 = *(const uint4*)(Ab + (size_t)(m0 + srow) * lda + k0 + skof);
        uint4 a1 = *(const uint4*)(Ab + (size_t)(m0 + 64 + srow) * lda + k0 + skof);
        uint4 b0 = *(const uint4*)(Bb + (size_t)(n0 + srow) * ldb + k0 + skof);
        uint4 b1 = *(const uint4*)(Bb + (size_t)(n0 + 64 + srow) * ldb + k0 + skof);
        __syncthreads();  // previous iter's LDS reads complete
        *(uint4*)&As[srow * 32 + skof]        = a0;
        *(uint4*)&As[(64 + srow) * 32 + skof] = a1;
        *(uint4*)&Bs[srow * 32 + skof]        = b0;
        *(uint4*)&Bs[(64 + srow) * 32 + skof] = b1;
        __syncthreads();
        bf16x8 af[4], bf[4];
#pragma unroll
        for (int i = 0; i < 4; ++i) af[i] = *(const bf16x8*)&As[(wm + i * 16 + lr) * 32 + lq * 8];
#pragma unroll
        for (int j = 0; j < 4; ++j) bf[j] = *(const bf16x8*)&Bs[(wn + j * 16 + lr) * 32 + lq * 8];
#pragma unroll
        for (int i = 0; i < 4; ++i)
#pragma unroll
            for (int j = 0; j < 4; ++j)
                acc[i][j] = __builtin_amdgcn_mfma_f32_16x16x32_bf16(af[i], bf[j], acc[i][j], 0, 0, 0);
    }

    // epilogue: lane L, reg r -> row = lq*4 + r, col = lr (within 16x16 tile)
#pragma unroll
    for (int i = 0; i < 4; ++i) {
#pragma unroll
        for (int r = 0; r < 4; ++r) {
            int row = m0 + wm + i * 16 + lq * 4 + r;
            float brow = (BIASMODE == 1) ? bias[row] : 0.f;
#pragma unroll
            for (int j = 0; j < 4; ++j) {
                int col = n0 + wn + j * 16 + lr;
                float v = acc[i][j][r] * scale;
                if (BIASMODE == 1) v += brow;
                if (BIASMODE == 2) v += bias[col];
                if (RELU) v = fmaxf(v, 0.f);
                size_t off = (size_t)b * strideC + (size_t)row * ldc + col;
                if (RESID) v += resid[off];
                if (OUTBF16) ((unsigned short*)C)[off] = f2bf(v);
                else         ((float*)C)[off] = v;
            }
        }
    }
}

extern "C" void kernel_launch(void* const* d_in, const int* in_sizes, int n_in,
                              void* d_out, int out_size, void* d_ws, size_t ws_size,
                              hipStream_t stream) {
    const float* x     = (const float*)d_in[0];
    const float* bn1_g = (const float*)d_in[1];
    const float* bn1_b = (const float*)d_in[2];
    const float* W_qkv = (const float*)d_in[3];
    const float* b_qkv = (const float*)d_in[4];
    const float* bn2_g = (const float*)d_in[5];
    const float* bn2_b = (const float*)d_in[6];
    const float* W1    = (const float*)d_in[7];
    const float* b1    = (const float*)d_in[8];
    const float* W2    = (const float*)d_in[9];
    const float* b2    = (const float*)d_in[10];
    float* out = (float*)d_out;
    char* ws = (char*)d_ws;

    // workspace layout (bytes), ~144 MB total:
    unsigned short* hT    = (unsigned short*)(ws);                 // 32M B  (hT -> ybnT)
    unsigned short* qkT   = (unsigned short*)(ws + 33554432);      // 8M B
    unsigned short* v     = (unsigned short*)(ws + 41943040);      // 32M B  (v -> y1T)
    unsigned short* betaT = (unsigned short*)(ws + 75497472);      // 64M B
    unsigned short* Wqkvb = (unsigned short*)(ws + 142606336);     // 640K B
    unsigned short* W1b   = (unsigned short*)(ws + 143261696);     // 512K B
    unsigned short* W2b   = (unsigned short*)(ws + 143785984);     // 512K B
    float* stats = (float*)(ws + 144310272);                       // 2048 f32
    float* mean1 = stats,        *rstd1 = stats + 512;
    float* mean2 = stats + 1024, *rstd2 = stats + 1536;
    unsigned short* ybnT = hT;
    unsigned short* y1T  = v;

    const long sHT = (long)HWN * CC;    // 1024*512
    const long sQK = (long)HWN * 128;   // 1024*128
    const long sV  = (long)CC * HWN;    // 512*1024
    const long sBT = (long)HWN * HWN;   // 1024*1024

    // 0. weights -> bf16
    cvt_bf16_kernel<<<(OO * CC + 255) / 256, 256, 0, stream>>>(W_qkv, Wqkvb, OO * CC);
    cvt_bf16_kernel<<<(CC * CC + 255) / 256, 256, 0, stream>>>(W1, W1b, CC * CC);
    cvt_bf16_kernel<<<(CC * CC + 255) / 256, 256, 0, stream>>>(W2, W2b, CC * CC);
    // 1. bn1 stats
    bn_stats_kernel<<<CC, 256, 0, stream>>>(x, mean1, rstd1);
    // 2. hT[b][s][c] = relu(bn1(x)) transposed, bf16
    bn_apply_t_kernel<true><<<dim3(16, 8, BB), 256, 0, stream>>>(x, mean1, rstd1, bn1_g, bn1_b, hT);
    // 3a. qkT[s][o'] = hT @ Wqk^T + b_qkv[o']   (M=1024, N=128, K=512), col bias
    mfma_gemm<true, 2, false, false><<<dim3(1, 8, BB), 256, 0, stream>>>(
        hT, Wqkvb, b_qkv, nullptr, qkT, 512, 512, 512, 128, sHT, 0, sQK, 1.f);
    // 3b. v[c][s] = Wv @ h + b_qkv[128+c]       (M=512, N=1024, K=512), row bias
    mfma_gemm<true, 1, false, false><<<dim3(8, 4, BB), 256, 0, stream>>>(
        Wqkvb + 128 * 512, hT, b_qkv + 128, nullptr, v, 512, 512, 512, 1024, 0, sHT, sV, 1.f);
    // 4. betaT[kj][qi] = (kT @ qT^T)/8          (M=1024, N=1024, K=64)
    mfma_gemm<true, 0, false, false><<<dim3(8, 8, BB), 256, 0, stream>>>(
        qkT + 64, qkT, nullptr, nullptr, betaT, 64, 128, 128, 1024, sQK, sQK, sBT, 0.125f);
    // 5. row softmax -> pT (in place)
    softmax_row_kernel<<<(BB * HWN) / 4, 256, 0, stream>>>(betaT);
    // 6. xr[c][s] = v @ pT^T + x -> d_out fp32  (M=512, N=1024, K=1024)
    mfma_gemm<false, 0, false, true><<<dim3(8, 4, BB), 256, 0, stream>>>(
        v, betaT, nullptr, x, out, 1024, 1024, 1024, 1024, sV, sBT, sV, 1.f);
    // 7. bn2 stats on xr
    bn_stats_kernel<<<CC, 256, 0, stream>>>(out, mean2, rstd2);
    // 8. ybnT[s][c] = bn2(xr) transposed, bf16 (aliases hT)
    bn_apply_t_kernel<false><<<dim3(16, 8, BB), 256, 0, stream>>>(out, mean2, rstd2, bn2_g, bn2_b, ybnT);
    // 9. y1T[s][o] = relu(ybnT @ W1^T + b1)     (M=1024, N=512, K=512), col bias (aliases v)
    mfma_gemm<true, 2, true, false><<<dim3(4, 8, BB), 256, 0, stream>>>(
        ybnT, W1b, b1, nullptr, y1T, 512, 512, 512, 512, sHT, 0, sHT, 1.f);
    // 10. out[c][s] = W2 @ y1T^T + b2 + xr      (M=512, N=1024, K=512), in-place resid
    mfma_gemm<false, 1, false, true><<<dim3(8, 4, BB), 256, 0, stream>>>(
        W2b, y1T, b2, out, out, 512, 512, 512, 1024, 0, sHT, sV, 1.f);
}

// Round 4
// 425.893 us; speedup vs baseline: 3.6771x; 1.2106x over previous
//
#include <hip/hip_runtime.h>

#define BB 32
#define CC 512
#define HWN 1024
#define DD 64
#define OO 640  // 2*DD + CC

typedef short bf16x8 __attribute__((ext_vector_type(8)));
typedef float f32x4 __attribute__((ext_vector_type(4)));
typedef __attribute__((address_space(1))) const void gvoid;
typedef __attribute__((address_space(3))) void svoid;

__device__ __forceinline__ void gload_lds16(const void* g, void* l) {
    __builtin_amdgcn_global_load_lds((gvoid*)g, (svoid*)l, 16, 0, 0);
}

__device__ __forceinline__ unsigned short f2bf(float f) {
    unsigned int u = __float_as_uint(f);
    unsigned int r = u + 0x7FFFu + ((u >> 16) & 1u);  // RNE
    return (unsigned short)(r >> 16);
}
__device__ __forceinline__ float bf2f(unsigned short h) {
    return __uint_as_float(((unsigned int)h) << 16);
}

// ---------------- f32 -> bf16 convert (weights) ----------------
__global__ __launch_bounds__(256) void cvt_bf16_kernel(const float* __restrict__ in,
                                                       unsigned short* __restrict__ out, int n) {
    int i = blockIdx.x * 256 + threadIdx.x;
    if (i < n) out[i] = f2bf(in[i]);
}

// ---------------- BN stats: one block per channel; input f32 or bf16 ----------------
template <bool INBF16>
__global__ __launch_bounds__(256) void bn_stats_kernel(const void* __restrict__ xv,
                                                       float* __restrict__ mean,
                                                       float* __restrict__ rstd) {
    int c = blockIdx.x;
    int t = threadIdx.x;
    float s = 0.f, s2 = 0.f;
    if (INBF16) {
        const unsigned int* x = (const unsigned int*)xv;  // 2 bf16 per uint
        for (int b = 0; b < BB; ++b) {
            const unsigned int* p = x + ((size_t)b * CC + c) * (HWN / 2);
#pragma unroll
            for (int i = 0; i < 2; ++i) {
                unsigned int w = p[t + i * 256];
                float v0 = bf2f((unsigned short)(w & 0xffffu));
                float v1 = bf2f((unsigned short)(w >> 16));
                s += v0 + v1; s2 += v0 * v0 + v1 * v1;
            }
        }
    } else {
        const float* x = (const float*)xv;
        for (int b = 0; b < BB; ++b) {
            const float* p = x + ((size_t)b * CC + c) * HWN;
#pragma unroll
            for (int i = 0; i < 4; ++i) {
                float v = p[t + i * 256];
                s += v; s2 += v * v;
            }
        }
    }
    for (int off = 32; off > 0; off >>= 1) {
        s  += __shfl_down(s,  off, 64);
        s2 += __shfl_down(s2, off, 64);
    }
    __shared__ float sh[4], sh2[4];
    int wave = t >> 6;
    if ((t & 63) == 0) { sh[wave] = s; sh2[wave] = s2; }
    __syncthreads();
    if (t == 0) {
        float ts = 0.f, ts2 = 0.f;
        for (int w = 0; w < 4; ++w) { ts += sh[w]; ts2 += sh2[w]; }
        const float invN = 1.f / (float)(BB * HWN);
        float m = ts * invN;
        float var = ts2 * invN - m * m;
        mean[c] = m;
        rstd[c] = rsqrtf(var + 1e-5f);
    }
}

// ------- BN apply + transpose: x[b][c][s] -> outT[b][s][c] bf16 (+relu) -------
template <bool RELU, bool INBF16>
__global__ __launch_bounds__(256) void bn_apply_t_kernel(const void* __restrict__ xv,
                                                         const float* __restrict__ mean,
                                                         const float* __restrict__ rstd,
                                                         const float* __restrict__ g,
                                                         const float* __restrict__ bta,
                                                         unsigned short* __restrict__ outT) {
    __shared__ float tile[64][65];
    int b  = blockIdx.z;
    int c0 = blockIdx.y * 64;
    int s0 = blockIdx.x * 64;
    int t = threadIdx.x;
    int sl = t & 63, grp = t >> 6;
#pragma unroll
    for (int i = 0; i < 16; ++i) {
        int cr = i * 4 + grp;
        int c = c0 + cr;
        float r  = rstd[c] * g[c];
        float sh = bta[c] - mean[c] * r;
        float xval;
        if (INBF16) {
            const unsigned short* xb = (const unsigned short*)xv;
            xval = bf2f(xb[((size_t)b * CC + c0 + cr) * HWN + s0 + sl]);
        } else {
            const float* xb = (const float*)xv;
            xval = xb[((size_t)b * CC + c0 + cr) * HWN + s0 + sl];
        }
        float v = fmaf(xval, r, sh);
        if (RELU) v = fmaxf(v, 0.f);
        tile[cr][sl] = v;
    }
    __syncthreads();
    unsigned short* ob = outT + ((size_t)b * HWN + s0) * CC + c0;
#pragma unroll
    for (int i = 0; i < 16; ++i) {
        int srow = i * 4 + grp;
        ob[(size_t)srow * CC + sl] = f2bf(tile[sl][srow]);
    }
}

// ---------------- row softmax on bf16 [nrows][1024], in place ----------------
__global__ __launch_bounds__(256) void softmax_row_kernel(unsigned short* __restrict__ p) {
    int row = blockIdx.x * 4 + (threadIdx.x >> 6);
    int L = threadIdx.x & 63;
    unsigned short* pr = p + (size_t)row * HWN;
    uint4 d0 = *(const uint4*)(pr + L * 16);
    uint4 d1 = *(const uint4*)(pr + L * 16 + 8);
    float v[16];
    unsigned int w[8] = {d0.x, d0.y, d0.z, d0.w, d1.x, d1.y, d1.z, d1.w};
#pragma unroll
    for (int i = 0; i < 8; ++i) {
        v[2 * i]     = bf2f((unsigned short)(w[i] & 0xffffu));
        v[2 * i + 1] = bf2f((unsigned short)(w[i] >> 16));
    }
    float m = -1e30f;
#pragma unroll
    for (int i = 0; i < 16; ++i) m = fmaxf(m, v[i]);
    for (int off = 32; off > 0; off >>= 1) m = fmaxf(m, __shfl_xor(m, off, 64));
    float s = 0.f;
#pragma unroll
    for (int i = 0; i < 16; ++i) { v[i] = __expf(v[i] - m); s += v[i]; }
    for (int off = 32; off > 0; off >>= 1) s += __shfl_xor(s, off, 64);
    float inv = 1.f / s;
    unsigned int o[8];
#pragma unroll
    for (int i = 0; i < 8; ++i) {
        unsigned int lo = f2bf(v[2 * i] * inv);
        unsigned int hi = f2bf(v[2 * i + 1] * inv);
        o[i] = lo | (hi << 16);
    }
    *(uint4*)(pr + L * 16)     = make_uint4(o[0], o[1], o[2], o[3]);
    *(uint4*)(pr + L * 16 + 8) = make_uint4(o[4], o[5], o[6], o[7]);
}

// ---------------- MFMA bf16 GEMM: C[b] = scale*(A @ Bt^T) (+bias)(+relu)(+resid) ----
// A:  M x K bf16 row-major (k-contiguous), Bt: N x K bf16 row-major (k-contiguous).
// C: M x N (fp32 or bf16), resid fp32 or bf16, same geometry as C.
// Tile 128x128, BK=32, 256 thr = 4 waves (2x2 of 64x64), global_load_lds staging.
template <bool OUTBF16, int BIASMODE /*0 none,1 row,2 col*/, bool RELU, int RESMODE /*0,1=f32,2=bf16*/>
__global__ __launch_bounds__(256) void mfma_gemm(const unsigned short* __restrict__ A,
                                                 const unsigned short* __restrict__ Bt,
                                                 const float* __restrict__ bias,
                                                 const void* __restrict__ resid,
                                                 void* __restrict__ C,
                                                 int K, int lda, int ldb, int ldc,
                                                 long strideA, long strideB, long strideC,
                                                 float scale) {
    __shared__ __align__(16) unsigned short As[128 * 32];
    __shared__ __align__(16) unsigned short Bs[128 * 32];
    int b  = blockIdx.z;
    int m0 = blockIdx.y * 128;
    int n0 = blockIdx.x * 128;
    const unsigned short* Ab = A  + (size_t)b * strideA;
    const unsigned short* Bb = Bt + (size_t)b * strideB;
    int t = threadIdx.x;
    int wv = t >> 6, L = t & 63;
    int wm = (wv >> 1) * 64, wn = (wv & 1) * 64;
    int lr = L & 15, lq = L >> 4;
    int srow = t >> 2;          // 0..63
    int skof = (t & 3) * 8;     // bf16 elems: 0,8,16,24
    // LDS dest byte offset for this thread's 16B chunk: t*16 (wave-uniform base + lane*16)
    unsigned short* ldsA0 = As + t * 8;
    unsigned short* ldsA1 = As + 64 * 32 + t * 8;
    unsigned short* ldsB0 = Bs + t * 8;
    unsigned short* ldsB1 = Bs + 64 * 32 + t * 8;

    f32x4 acc[4][4] = {};

    for (int k0 = 0; k0 < K; k0 += 32) {
        __syncthreads();  // prior iter's LDS reads complete before overwrite
        gload_lds16(Ab + (size_t)(m0 + srow) * lda + k0 + skof, ldsA0);
        gload_lds16(Ab + (size_t)(m0 + 64 + srow) * lda + k0 + skof, ldsA1);
        gload_lds16(Bb + (size_t)(n0 + srow) * ldb + k0 + skof, ldsB0);
        gload_lds16(Bb + (size_t)(n0 + 64 + srow) * ldb + k0 + skof, ldsB1);
        __syncthreads();  // vmcnt(0) drained before barrier -> LDS ready
        bf16x8 af[4], bf[4];
#pragma unroll
        for (int i = 0; i < 4; ++i) af[i] = *(const bf16x8*)&As[(wm + i * 16 + lr) * 32 + lq * 8];
#pragma unroll
        for (int j = 0; j < 4; ++j) bf[j] = *(const bf16x8*)&Bs[(wn + j * 16 + lr) * 32 + lq * 8];
#pragma unroll
        for (int i = 0; i < 4; ++i)
#pragma unroll
            for (int j = 0; j < 4; ++j)
                acc[i][j] = __builtin_amdgcn_mfma_f32_16x16x32_bf16(af[i], bf[j], acc[i][j], 0, 0, 0);
    }

    // epilogue: lane L, reg r -> row = lq*4 + r, col = lr (within 16x16 tile)
#pragma unroll
    for (int i = 0; i < 4; ++i) {
#pragma unroll
        for (int r = 0; r < 4; ++r) {
            int row = m0 + wm + i * 16 + lq * 4 + r;
            float brow = (BIASMODE == 1) ? bias[row] : 0.f;
#pragma unroll
            for (int j = 0; j < 4; ++j) {
                int col = n0 + wn + j * 16 + lr;
                float v = acc[i][j][r] * scale;
                if (BIASMODE == 1) v += brow;
                if (BIASMODE == 2) v += bias[col];
                if (RELU) v = fmaxf(v, 0.f);
                size_t off = (size_t)b * strideC + (size_t)row * ldc + col;
                if (RESMODE == 1) v += ((const float*)resid)[off];
                if (RESMODE == 2) v += bf2f(((const unsigned short*)resid)[off]);
                if (OUTBF16) ((unsigned short*)C)[off] = f2bf(v);
                else         ((float*)C)[off] = v;
            }
        }
    }
}

extern "C" void kernel_launch(void* const* d_in, const int* in_sizes, int n_in,
                              void* d_out, int out_size, void* d_ws, size_t ws_size,
                              hipStream_t stream) {
    const float* x     = (const float*)d_in[0];
    const float* bn1_g = (const float*)d_in[1];
    const float* bn1_b = (const float*)d_in[2];
    const float* W_qkv = (const float*)d_in[3];
    const float* b_qkv = (const float*)d_in[4];
    const float* bn2_g = (const float*)d_in[5];
    const float* bn2_b = (const float*)d_in[6];
    const float* W1    = (const float*)d_in[7];
    const float* b1    = (const float*)d_in[8];
    const float* W2    = (const float*)d_in[9];
    const float* b2    = (const float*)d_in[10];
    float* out = (float*)d_out;
    char* ws = (char*)d_ws;

    // workspace layout (bytes), ~170 MB total:
    unsigned short* hT    = (unsigned short*)(ws);                 // 32 MB (hT -> ybnT)
    unsigned short* qkT   = (unsigned short*)(ws + 33554432);      // 8 MB
    unsigned short* v     = (unsigned short*)(ws + 41943040);      // 32 MB (v -> y1T)
    unsigned short* betaT = (unsigned short*)(ws + 75497472);      // 64 MB
    unsigned short* xr    = (unsigned short*)(ws + 142606336);     // 32 MB (bf16 xr)
    unsigned short* Wqkvb = (unsigned short*)(ws + 176160768);     // 640 KB
    unsigned short* W1b   = (unsigned short*)(ws + 176816128);     // 512 KB
    unsigned short* W2b   = (unsigned short*)(ws + 177340416);     // 512 KB
    float* stats = (float*)(ws + 177864704);                       // 2048 f32
    float* mean1 = stats,        *rstd1 = stats + 512;
    float* mean2 = stats + 1024, *rstd2 = stats + 1536;
    unsigned short* ybnT = hT;
    unsigned short* y1T  = v;

    const long sHT = (long)HWN * CC;    // 1024*512
    const long sQK = (long)HWN * 128;   // 1024*128
    const long sV  = (long)CC * HWN;    // 512*1024
    const long sBT = (long)HWN * HWN;   // 1024*1024

    // 0. weights -> bf16
    cvt_bf16_kernel<<<(OO * CC + 255) / 256, 256, 0, stream>>>(W_qkv, Wqkvb, OO * CC);
    cvt_bf16_kernel<<<(CC * CC + 255) / 256, 256, 0, stream>>>(W1, W1b, CC * CC);
    cvt_bf16_kernel<<<(CC * CC + 255) / 256, 256, 0, stream>>>(W2, W2b, CC * CC);
    // 1. bn1 stats (fp32 x)
    bn_stats_kernel<false><<<CC, 256, 0, stream>>>(x, mean1, rstd1);
    // 2. hT[b][s][c] = relu(bn1(x)) transposed, bf16
    bn_apply_t_kernel<true, false><<<dim3(16, 8, BB), 256, 0, stream>>>(x, mean1, rstd1, bn1_g, bn1_b, hT);
    // 3a. qkT[s][o'] = hT @ Wqk^T + b_qkv[o']   (M=1024, N=128, K=512), col bias
    mfma_gemm<true, 2, false, 0><<<dim3(1, 8, BB), 256, 0, stream>>>(
        hT, Wqkvb, b_qkv, nullptr, qkT, 512, 512, 512, 128, sHT, 0, sQK, 1.f);
    // 3b. v[c][s] = Wv @ h + b_qkv[128+c]       (M=512, N=1024, K=512), row bias
    mfma_gemm<true, 1, false, 0><<<dim3(8, 4, BB), 256, 0, stream>>>(
        Wqkvb + 128 * 512, hT, b_qkv + 128, nullptr, v, 512, 512, 512, 1024, 0, sHT, sV, 1.f);
    // 4. betaT[kj][qi] = (kT @ qT^T)/8          (M=1024, N=1024, K=64)
    mfma_gemm<true, 0, false, 0><<<dim3(8, 8, BB), 256, 0, stream>>>(
        qkT + 64, qkT, nullptr, nullptr, betaT, 64, 128, 128, 1024, sQK, sQK, sBT, 0.125f);
    // 5. row softmax -> pT (in place)
    softmax_row_kernel<<<(BB * HWN) / 4, 256, 0, stream>>>(betaT);
    // 6. xr[c][s] = v @ pT^T + x, bf16 out      (M=512, N=1024, K=1024), fp32 resid
    mfma_gemm<true, 0, false, 1><<<dim3(8, 4, BB), 256, 0, stream>>>(
        v, betaT, nullptr, x, xr, 1024, 1024, 1024, 1024, sV, sBT, sV, 1.f);
    // 7. bn2 stats on xr (bf16)
    bn_stats_kernel<true><<<CC, 256, 0, stream>>>(xr, mean2, rstd2);
    // 8. ybnT[s][c] = bn2(xr) transposed, bf16 (aliases hT)
    bn_apply_t_kernel<false, true><<<dim3(16, 8, BB), 256, 0, stream>>>(xr, mean2, rstd2, bn2_g, bn2_b, ybnT);
    // 9. y1T[s][o] = relu(ybnT @ W1^T + b1)     (M=1024, N=512, K=512), col bias (aliases v)
    mfma_gemm<true, 2, true, 0><<<dim3(4, 8, BB), 256, 0, stream>>>(
        ybnT, W1b, b1, nullptr, y1T, 512, 512, 512, 512, sHT, 0, sHT, 1.f);
    // 10. out[c][s] = W2 @ y1T^T + b2 + xr(bf16) -> d_out fp32  (M=512, N=1024, K=512)
    mfma_gemm<false, 1, false, 2><<<dim3(8, 4, BB), 256, 0, stream>>>(
        W2b, y1T, b2, xr, out, 512, 512, 512, 1024, 0, sHT, sV, 1.f);
}

// Round 5
// 416.760 us; speedup vs baseline: 3.7577x; 1.0219x over previous
//
#include <hip/hip_runtime.h>

#define BB 32
#define CC 512
#define HWN 1024
#define DD 64
#define OO 640  // 2*DD + CC

typedef short bf16x8 __attribute__((ext_vector_type(8)));
typedef float f32x4 __attribute__((ext_vector_type(4)));
typedef __attribute__((address_space(1))) const void gvoid;
typedef __attribute__((address_space(3))) void svoid;

__device__ __forceinline__ void gload_lds16(const void* g, void* l) {
    __builtin_amdgcn_global_load_lds((gvoid*)g, (svoid*)l, 16, 0, 0);
}

__device__ __forceinline__ unsigned short f2bf(float f) {
    unsigned int u = __float_as_uint(f);
    unsigned int r = u + 0x7FFFu + ((u >> 16) & 1u);  // RNE
    return (unsigned short)(r >> 16);
}
__device__ __forceinline__ float bf2f(unsigned short h) {
    return __uint_as_float(((unsigned int)h) << 16);
}

// ---------------- f32 -> bf16 convert (weights) ----------------
__global__ __launch_bounds__(256) void cvt_bf16_kernel(const float* __restrict__ in,
                                                       unsigned short* __restrict__ out, int n) {
    int i = blockIdx.x * 256 + threadIdx.x;
    if (i < n) out[i] = f2bf(in[i]);
}

// ---------------- BN stats: one block per channel; input f32 or bf16 ----------------
template <bool INBF16>
__global__ __launch_bounds__(256) void bn_stats_kernel(const void* __restrict__ xv,
                                                       float* __restrict__ mean,
                                                       float* __restrict__ rstd) {
    int c = blockIdx.x;
    int t = threadIdx.x;
    float s = 0.f, s2 = 0.f;
    if (INBF16) {
        const unsigned int* x = (const unsigned int*)xv;  // 2 bf16 per uint
        for (int b = 0; b < BB; ++b) {
            const unsigned int* p = x + ((size_t)b * CC + c) * (HWN / 2);
#pragma unroll
            for (int i = 0; i < 2; ++i) {
                unsigned int w = p[t + i * 256];
                float v0 = bf2f((unsigned short)(w & 0xffffu));
                float v1 = bf2f((unsigned short)(w >> 16));
                s += v0 + v1; s2 += v0 * v0 + v1 * v1;
            }
        }
    } else {
        const float* x = (const float*)xv;
        for (int b = 0; b < BB; ++b) {
            const float* p = x + ((size_t)b * CC + c) * HWN;
#pragma unroll
            for (int i = 0; i < 4; ++i) {
                float v = p[t + i * 256];
                s += v; s2 += v * v;
            }
        }
    }
    for (int off = 32; off > 0; off >>= 1) {
        s  += __shfl_down(s,  off, 64);
        s2 += __shfl_down(s2, off, 64);
    }
    __shared__ float sh[4], sh2[4];
    int wave = t >> 6;
    if ((t & 63) == 0) { sh[wave] = s; sh2[wave] = s2; }
    __syncthreads();
    if (t == 0) {
        float ts = 0.f, ts2 = 0.f;
        for (int w = 0; w < 4; ++w) { ts += sh[w]; ts2 += sh2[w]; }
        const float invN = 1.f / (float)(BB * HWN);
        float m = ts * invN;
        float var = ts2 * invN - m * m;
        mean[c] = m;
        rstd[c] = rsqrtf(var + 1e-5f);
    }
}

// ------- BN apply + transpose: x[b][c][s] -> outT[b][s][c] bf16 (+relu) -------
template <bool RELU, bool INBF16>
__global__ __launch_bounds__(256) void bn_apply_t_kernel(const void* __restrict__ xv,
                                                         const float* __restrict__ mean,
                                                         const float* __restrict__ rstd,
                                                         const float* __restrict__ g,
                                                         const float* __restrict__ bta,
                                                         unsigned short* __restrict__ outT) {
    __shared__ float tile[64][65];
    int b  = blockIdx.z;
    int c0 = blockIdx.y * 64;
    int s0 = blockIdx.x * 64;
    int t = threadIdx.x;
    int sl = t & 63, grp = t >> 6;
#pragma unroll
    for (int i = 0; i < 16; ++i) {
        int cr = i * 4 + grp;
        int c = c0 + cr;
        float r  = rstd[c] * g[c];
        float sh = bta[c] - mean[c] * r;
        float xval;
        if (INBF16) {
            const unsigned short* xb = (const unsigned short*)xv;
            xval = bf2f(xb[((size_t)b * CC + c0 + cr) * HWN + s0 + sl]);
        } else {
            const float* xb = (const float*)xv;
            xval = xb[((size_t)b * CC + c0 + cr) * HWN + s0 + sl];
        }
        float v = fmaf(xval, r, sh);
        if (RELU) v = fmaxf(v, 0.f);
        tile[cr][sl] = v;
    }
    __syncthreads();
    unsigned short* ob = outT + ((size_t)b * HWN + s0) * CC + c0;
#pragma unroll
    for (int i = 0; i < 16; ++i) {
        int srow = i * 4 + grp;
        ob[(size_t)srow * CC + sl] = f2bf(tile[sl][srow]);
    }
}

// ---------------- row softmax on bf16 [nrows][1024], in place ----------------
__global__ __launch_bounds__(256) void softmax_row_kernel(unsigned short* __restrict__ p) {
    int row = blockIdx.x * 4 + (threadIdx.x >> 6);
    int L = threadIdx.x & 63;
    unsigned short* pr = p + (size_t)row * HWN;
    uint4 d0 = *(const uint4*)(pr + L * 16);
    uint4 d1 = *(const uint4*)(pr + L * 16 + 8);
    float v[16];
    unsigned int w[8] = {d0.x, d0.y, d0.z, d0.w, d1.x, d1.y, d1.z, d1.w};
#pragma unroll
    for (int i = 0; i < 8; ++i) {
        v[2 * i]     = bf2f((unsigned short)(w[i] & 0xffffu));
        v[2 * i + 1] = bf2f((unsigned short)(w[i] >> 16));
    }
    float m = -1e30f;
#pragma unroll
    for (int i = 0; i < 16; ++i) m = fmaxf(m, v[i]);
    for (int off = 32; off > 0; off >>= 1) m = fmaxf(m, __shfl_xor(m, off, 64));
    float s = 0.f;
#pragma unroll
    for (int i = 0; i < 16; ++i) { v[i] = __expf(v[i] - m); s += v[i]; }
    for (int off = 32; off > 0; off >>= 1) s += __shfl_xor(s, off, 64);
    float inv = 1.f / s;
    unsigned int o[8];
#pragma unroll
    for (int i = 0; i < 8; ++i) {
        unsigned int lo = f2bf(v[2 * i] * inv);
        unsigned int hi = f2bf(v[2 * i + 1] * inv);
        o[i] = lo | (hi << 16);
    }
    *(uint4*)(pr + L * 16)     = make_uint4(o[0], o[1], o[2], o[3]);
    *(uint4*)(pr + L * 16 + 8) = make_uint4(o[4], o[5], o[6], o[7]);
}

// ---------------- MFMA bf16 GEMM: C[b] = scale*(A @ Bt^T) (+bias)(+relu)(+resid) ----
// A:  M x K bf16 row-major (k-contiguous), Bt: N x K bf16 row-major (k-contiguous).
// C: M x N (fp32 or bf16), resid fp32 or bf16, same geometry as C.
// Tile 128x128, BK=32, 256 thr = 4 waves (2x2 of 64x64).
// Double-buffered LDS w/ global_load_lds (1 barrier/iter); XOR-swizzled chunk
// placement (slot = chunk ^ ((row>>1)&3)) -> conflict-free ds_read_b128.
template <bool OUTBF16, int BIASMODE /*0 none,1 row,2 col*/, bool RELU, int RESMODE /*0,1=f32,2=bf16*/>
__global__ __launch_bounds__(256) void mfma_gemm(const unsigned short* __restrict__ A,
                                                 const unsigned short* __restrict__ Bt,
                                                 const float* __restrict__ bias,
                                                 const void* __restrict__ resid,
                                                 void* __restrict__ C,
                                                 int K, int lda, int ldb, int ldc,
                                                 long strideA, long strideB, long strideC,
                                                 float scale) {
    __shared__ __align__(16) unsigned short As[2][128 * 32];
    __shared__ __align__(16) unsigned short Bs[2][128 * 32];
    int b  = blockIdx.z;
    int m0 = blockIdx.y * 128;
    int n0 = blockIdx.x * 128;
    const unsigned short* Ab = A  + (size_t)b * strideA;
    const unsigned short* Bb = Bt + (size_t)b * strideB;
    int t = threadIdx.x;
    int wv = t >> 6, L = t & 63;
    int wm = (wv >> 1) * 64, wn = (wv & 1) * 64;
    int lr = L & 15, lq = L >> 4;
    int srow = t >> 2;                       // staged row 0..63 (per half)
    int gchunk = (t & 3) ^ ((t >> 3) & 3);   // global 16B chunk, swizzle-matched
    int skof = gchunk * 8;                   // bf16 elem offset in k
    int swz = (lr >> 1) & 3;                 // read-side swizzle

    // fragment read offsets (elems), fixed across iters
    int aoff[4], boff[4];
#pragma unroll
    for (int i = 0; i < 4; ++i) {
        aoff[i] = (wm + i * 16 + lr) * 32 + ((lq ^ swz) * 8);
        boff[i] = (wn + i * 16 + lr) * 32 + ((lq ^ swz) * 8);
    }

    const unsigned short* gA0 = Ab + (size_t)(m0 + srow) * lda + skof;
    const unsigned short* gA1 = Ab + (size_t)(m0 + 64 + srow) * lda + skof;
    const unsigned short* gB0 = Bb + (size_t)(n0 + srow) * ldb + skof;
    const unsigned short* gB1 = Bb + (size_t)(n0 + 64 + srow) * ldb + skof;

    f32x4 acc[4][4] = {};
    int nIter = K >> 5;

    // prologue: stage tile 0 into buffer 0
    gload_lds16(gA0, &As[0][t * 8]);
    gload_lds16(gA1, &As[0][64 * 32 + t * 8]);
    gload_lds16(gB0, &Bs[0][t * 8]);
    gload_lds16(gB1, &Bs[0][64 * 32 + t * 8]);

    int p = 0;
    for (int i = 0; i < nIter; ++i) {
        __syncthreads();  // vmcnt(0): buf[p] staged; all waves past buf[p^1] reads
        if (i + 1 < nIter) {
            int ko = (i + 1) << 5;
            gload_lds16(gA0 + ko, &As[p ^ 1][t * 8]);
            gload_lds16(gA1 + ko, &As[p ^ 1][64 * 32 + t * 8]);
            gload_lds16(gB0 + ko, &Bs[p ^ 1][t * 8]);
            gload_lds16(gB1 + ko, &Bs[p ^ 1][64 * 32 + t * 8]);
        }
        bf16x8 af[4], bfr[4];
#pragma unroll
        for (int j = 0; j < 4; ++j) af[j]  = *(const bf16x8*)&As[p][aoff[j]];
#pragma unroll
        for (int j = 0; j < 4; ++j) bfr[j] = *(const bf16x8*)&Bs[p][boff[j]];
#pragma unroll
        for (int ii = 0; ii < 4; ++ii)
#pragma unroll
            for (int jj = 0; jj < 4; ++jj)
                acc[ii][jj] = __builtin_amdgcn_mfma_f32_16x16x32_bf16(af[ii], bfr[jj], acc[ii][jj], 0, 0, 0);
        p ^= 1;
    }

    // epilogue: lane L, reg r -> row = lq*4 + r, col = lr (within 16x16 tile)
#pragma unroll
    for (int i = 0; i < 4; ++i) {
#pragma unroll
        for (int r = 0; r < 4; ++r) {
            int row = m0 + wm + i * 16 + lq * 4 + r;
            float brow = (BIASMODE == 1) ? bias[row] : 0.f;
#pragma unroll
            for (int j = 0; j < 4; ++j) {
                int col = n0 + wn + j * 16 + lr;
                float v = acc[i][j][r] * scale;
                if (BIASMODE == 1) v += brow;
                if (BIASMODE == 2) v += bias[col];
                if (RELU) v = fmaxf(v, 0.f);
                size_t off = (size_t)b * strideC + (size_t)row * ldc + col;
                if (RESMODE == 1) v += ((const float*)resid)[off];
                if (RESMODE == 2) v += bf2f(((const unsigned short*)resid)[off]);
                if (OUTBF16) ((unsigned short*)C)[off] = f2bf(v);
                else         ((float*)C)[off] = v;
            }
        }
    }
}

extern "C" void kernel_launch(void* const* d_in, const int* in_sizes, int n_in,
                              void* d_out, int out_size, void* d_ws, size_t ws_size,
                              hipStream_t stream) {
    const float* x     = (const float*)d_in[0];
    const float* bn1_g = (const float*)d_in[1];
    const float* bn1_b = (const float*)d_in[2];
    const float* W_qkv = (const float*)d_in[3];
    const float* b_qkv = (const float*)d_in[4];
    const float* bn2_g = (const float*)d_in[5];
    const float* bn2_b = (const float*)d_in[6];
    const float* W1    = (const float*)d_in[7];
    const float* b1    = (const float*)d_in[8];
    const float* W2    = (const float*)d_in[9];
    const float* b2    = (const float*)d_in[10];
    float* out = (float*)d_out;
    char* ws = (char*)d_ws;

    // workspace layout (bytes), ~170 MB total:
    unsigned short* hT    = (unsigned short*)(ws);                 // 32 MB (hT -> ybnT)
    unsigned short* qkT   = (unsigned short*)(ws + 33554432);      // 8 MB
    unsigned short* v     = (unsigned short*)(ws + 41943040);      // 32 MB (v -> y1T)
    unsigned short* betaT = (unsigned short*)(ws + 75497472);      // 64 MB
    unsigned short* xr    = (unsigned short*)(ws + 142606336);     // 32 MB (bf16 xr)
    unsigned short* Wqkvb = (unsigned short*)(ws + 176160768);     // 640 KB
    unsigned short* W1b   = (unsigned short*)(ws + 176816128);     // 512 KB
    unsigned short* W2b   = (unsigned short*)(ws + 177340416);     // 512 KB
    float* stats = (float*)(ws + 177864704);                       // 2048 f32
    float* mean1 = stats,        *rstd1 = stats + 512;
    float* mean2 = stats + 1024, *rstd2 = stats + 1536;
    unsigned short* ybnT = hT;
    unsigned short* y1T  = v;

    const long sHT = (long)HWN * CC;    // 1024*512
    const long sQK = (long)HWN * 128;   // 1024*128
    const long sV  = (long)CC * HWN;    // 512*1024
    const long sBT = (long)HWN * HWN;   // 1024*1024

    // 0. weights -> bf16
    cvt_bf16_kernel<<<(OO * CC + 255) / 256, 256, 0, stream>>>(W_qkv, Wqkvb, OO * CC);
    cvt_bf16_kernel<<<(CC * CC + 255) / 256, 256, 0, stream>>>(W1, W1b, CC * CC);
    cvt_bf16_kernel<<<(CC * CC + 255) / 256, 256, 0, stream>>>(W2, W2b, CC * CC);
    // 1. bn1 stats (fp32 x)
    bn_stats_kernel<false><<<CC, 256, 0, stream>>>(x, mean1, rstd1);
    // 2. hT[b][s][c] = relu(bn1(x)) transposed, bf16
    bn_apply_t_kernel<true, false><<<dim3(16, 8, BB), 256, 0, stream>>>(x, mean1, rstd1, bn1_g, bn1_b, hT);
    // 3a. qkT[s][o'] = hT @ Wqk^T + b_qkv[o']   (M=1024, N=128, K=512), col bias
    mfma_gemm<true, 2, false, 0><<<dim3(1, 8, BB), 256, 0, stream>>>(
        hT, Wqkvb, b_qkv, nullptr, qkT, 512, 512, 512, 128, sHT, 0, sQK, 1.f);
    // 3b. v[c][s] = Wv @ h + b_qkv[128+c]       (M=512, N=1024, K=512), row bias
    mfma_gemm<true, 1, false, 0><<<dim3(8, 4, BB), 256, 0, stream>>>(
        Wqkvb + 128 * 512, hT, b_qkv + 128, nullptr, v, 512, 512, 512, 1024, 0, sHT, sV, 1.f);
    // 4. betaT[kj][qi] = (kT @ qT^T)/8          (M=1024, N=1024, K=64)
    mfma_gemm<true, 0, false, 0><<<dim3(8, 8, BB), 256, 0, stream>>>(
        qkT + 64, qkT, nullptr, nullptr, betaT, 64, 128, 128, 1024, sQK, sQK, sBT, 0.125f);
    // 5. row softmax -> pT (in place)
    softmax_row_kernel<<<(BB * HWN) / 4, 256, 0, stream>>>(betaT);
    // 6. xr[c][s] = v @ pT^T + x, bf16 out      (M=512, N=1024, K=1024), fp32 resid
    mfma_gemm<true, 0, false, 1><<<dim3(8, 4, BB), 256, 0, stream>>>(
        v, betaT, nullptr, x, xr, 1024, 1024, 1024, 1024, sV, sBT, sV, 1.f);
    // 7. bn2 stats on xr (bf16)
    bn_stats_kernel<true><<<CC, 256, 0, stream>>>(xr, mean2, rstd2);
    // 8. ybnT[s][c] = bn2(xr) transposed, bf16 (aliases hT)
    bn_apply_t_kernel<false, true><<<dim3(16, 8, BB), 256, 0, stream>>>(xr, mean2, rstd2, bn2_g, bn2_b, ybnT);
    // 9. y1T[s][o] = relu(ybnT @ W1^T + b1)     (M=1024, N=512, K=512), col bias (aliases v)
    mfma_gemm<true, 2, true, 0><<<dim3(4, 8, BB), 256, 0, stream>>>(
        ybnT, W1b, b1, nullptr, y1T, 512, 512, 512, 512, sHT, 0, sHT, 1.f);
    // 10. out[c][s] = W2 @ y1T^T + b2 + xr(bf16) -> d_out fp32  (M=512, N=1024, K=512)
    mfma_gemm<false, 1, false, 2><<<dim3(8, 4, BB), 256, 0, stream>>>(
        W2b, y1T, b2, xr, out, 512, 512, 512, 1024, 0, sHT, sV, 1.f);
}